// Round 8
// baseline (46.000 us; speedup 1.0000x reference)
//
#include <hip/hip_runtime.h>

// Problem constants (from the reference)
#define BB 16
#define SS 4096
#define CC 512
#define NPOS (BB * SS)           // 65536 mask positions
#define OUT_ELEMS (BB * SS * CC) // 33554432 floats for `out`

#define POS_PER_BLK 32           // positions per block (divides 4096: no row-crossing)
#define F4_PER_POS (CC / 4)      // 128 float4 per position
#define F4_PER_BLK (POS_PER_BLK * F4_PER_POS)   // 4096 float4 per block
#define F4_PER_WAVE 1024         // each of 4 waves owns 8 positions

typedef float vfloat4 __attribute__((ext_vector_type(4)));

// ---------------- Threefry-2x32, 20 rounds, key = (0, 42) -------------------
// Partitionable counter-mode (JAX >= 0.4.30 default): per element i, hash
// x = (hi32(i), lo32(i)) = (0, i) with key (0, 42); 32-bit out = v0 ^ v1.
__device__ __forceinline__ unsigned rotl32(unsigned x, unsigned d) {
    return (x << d) | (x >> (32u - d));
}

__device__ __forceinline__ unsigned threefry_bits(unsigned i) {
    const unsigned k0 = 0u;
    const unsigned k1 = 42u;
    const unsigned k2 = 0u ^ 42u ^ 0x1BD11BDAu;
    unsigned v0 = 0u + k0;   // counts_hi + ks0
    unsigned v1 = i + k1;    // counts_lo + ks1

#define TF_RND(r) { v0 += v1; v1 = rotl32(v1, (r)); v1 ^= v0; }
    TF_RND(13) TF_RND(15) TF_RND(26) TF_RND(6)
    v0 += k1; v1 += k2 + 1u;
    TF_RND(17) TF_RND(29) TF_RND(16) TF_RND(24)
    v0 += k2; v1 += k0 + 2u;
    TF_RND(13) TF_RND(15) TF_RND(26) TF_RND(6)
    v0 += k0; v1 += k1 + 3u;
    TF_RND(17) TF_RND(29) TF_RND(16) TF_RND(24)
    v0 += k1; v1 += k2 + 4u;
    TF_RND(13) TF_RND(15) TF_RND(26) TF_RND(6)
    v0 += k2; v1 += k0 + 5u;
#undef TF_RND

    return v0 ^ v1;          // XOR-fold of the 2x32 PRF output
}

__device__ __forceinline__ int sparse_at(int i) {
    unsigned bits = threefry_bits((unsigned)i);
    unsigned fb = (bits >> 9) | 0x3f800000u;
    float u = __uint_as_float(fb) - 1.0f;   // uniform in [0,1), 23 mantissa bits
    return (u < 0.065f) ? 1 : 0;
}

// ---------------- Fused kernel: ballot mask + run-specialized copy ----------
// Block = 32 consecutive positions of one row; wave w owns positions
// [8w, 8w+8). Mask built in SGPRs via two ballots (no LDS/barriers). The
// wave's 8-bit mask slice picks one of three wave-uniform paths:
//   0x00: 16-deep load burst -> 16 stores (max vmcnt pipelining)
//   0xFF: 16 pure stores of preloaded mask_item (no loads)
//   else: per-position fallback (~40% of waves; spans are >=10 long)
__global__ __launch_bounds__(256) void fused_kernel(const vfloat4* __restrict__ seq,
                                                    const vfloat4* __restrict__ mi,
                                                    float* __restrict__ maskf,
                                                    vfloat4* __restrict__ out) {
    const int t = threadIdx.x;
    const int lane = t & 63;
    const int w = t >> 6;                   // wave id 0..3
    const int base = blockIdx.x * POS_PER_BLK;
    const int rowstart = base & ~(SS - 1);  // rows are 4096-aligned

    // Ballot 1: bit l = sparse(base-5+l), l = 0..40 (halo), clamped to row
    int sv = 0;
    {
        const int p = base - 5 + lane;
        if (lane <= 40 && p >= rowstart && p < rowstart + SS) sv = sparse_at(p);
    }
    const unsigned long long bal = __ballot(sv);

    // Ballot 2: bit t0 = dilated mask of position base+t0 (t0 = 0..31)
    int m_t = 0;
    if (lane < 32) {
        const int j = (base + lane) & (SS - 1);
        if (j == SS - 1) m_t = (int)((bal >> (lane + 5)) & 1ull);  // sparse only
        else             m_t = ((bal >> lane) & 0x3FFull) != 0ull; // window [j-5, j+4]
    }
    const unsigned M = (unsigned)__ballot(m_t);   // 32 mask bits, SGPR

    if (t < 32) maskf[base + t] = (float)((M >> t) & 1u);  // second output

    // Preload mask_item (cached; 2KB stays L1-resident). Wave base is
    // 1024-aligned so channel index is lane (even it) or 64+lane (odd it).
    const vfloat4 mi0 = mi[lane];
    const vfloat4 mi1 = mi[64 + lane];

    const long long wbase = (long long)blockIdx.x * F4_PER_BLK
                          + w * F4_PER_WAVE + lane;
    const vfloat4* sp = seq + wbase;
    vfloat4* op = out + wbase;
    const unsigned wmask = (M >> (w * 8)) & 0xFFu;   // SGPR, wave-uniform

    if (wmask == 0u) {
        vfloat4 v[16];
#pragma unroll
        for (int it = 0; it < 16; ++it) v[it] = __builtin_nontemporal_load(sp + it * 64);
#pragma unroll
        for (int it = 0; it < 16; ++it) __builtin_nontemporal_store(v[it], op + it * 64);
    } else if (wmask == 0xFFu) {
#pragma unroll
        for (int it = 0; it < 16; ++it)
            __builtin_nontemporal_store((it & 1) ? mi1 : mi0, op + it * 64);
    } else {
#pragma unroll
        for (int p = 0; p < 8; ++p) {
            if ((wmask >> p) & 1u) {
                __builtin_nontemporal_store(mi0, op + p * 128);
                __builtin_nontemporal_store(mi1, op + p * 128 + 64);
            } else {
                vfloat4 a = __builtin_nontemporal_load(sp + p * 128);
                vfloat4 b = __builtin_nontemporal_load(sp + p * 128 + 64);
                __builtin_nontemporal_store(a, op + p * 128);
                __builtin_nontemporal_store(b, op + p * 128 + 64);
            }
        }
    }
}

extern "C" void kernel_launch(void* const* d_in, const int* in_sizes, int n_in,
                              void* d_out, int out_size, void* d_ws, size_t ws_size,
                              hipStream_t stream) {
    const float* seq = (const float*)d_in[0];
    const float* mask_item = (const float*)d_in[1];
    float* out = (float*)d_out;
    float* maskf = out + OUT_ELEMS;         // tuple output #2 lives at the tail

    fused_kernel<<<NPOS / POS_PER_BLK, 256, 0, stream>>>((const vfloat4*)seq,
                                                         (const vfloat4*)mask_item,
                                                         maskf,
                                                         (vfloat4*)out);
}

// Round 9
// 35.636 us; speedup vs baseline: 1.2908x; 1.2908x over previous
//
#include <hip/hip_runtime.h>

// Problem constants (from the reference)
#define BB 16
#define SS 4096
#define CC 512
#define NPOS (BB * SS)           // 65536 mask positions
#define OUT_ELEMS (BB * SS * CC) // 33554432 floats for `out`

#define POS_PER_BLK 32           // positions per block (divides 4096: no row-crossing)
#define F4_PER_POS (CC / 4)      // 128 float4 per position
#define F4_PER_BLK (POS_PER_BLK * F4_PER_POS)   // 4096 float4 per block
#define F4_PER_WAVE 1024         // each of 4 waves owns 8 positions

typedef float vfloat4 __attribute__((ext_vector_type(4)));

// ---------------- Threefry-2x32, 20 rounds, key = (0, 42) -------------------
// Partitionable counter-mode (JAX >= 0.4.30 default): per element i, hash
// x = (hi32(i), lo32(i)) = (0, i) with key (0, 42); 32-bit out = v0 ^ v1.
__device__ __forceinline__ unsigned rotl32(unsigned x, unsigned d) {
    return (x << d) | (x >> (32u - d));
}

__device__ __forceinline__ unsigned threefry_bits(unsigned i) {
    const unsigned k0 = 0u;
    const unsigned k1 = 42u;
    const unsigned k2 = 0u ^ 42u ^ 0x1BD11BDAu;
    unsigned v0 = 0u + k0;   // counts_hi + ks0
    unsigned v1 = i + k1;    // counts_lo + ks1

#define TF_RND(r) { v0 += v1; v1 = rotl32(v1, (r)); v1 ^= v0; }
    TF_RND(13) TF_RND(15) TF_RND(26) TF_RND(6)
    v0 += k1; v1 += k2 + 1u;
    TF_RND(17) TF_RND(29) TF_RND(16) TF_RND(24)
    v0 += k2; v1 += k0 + 2u;
    TF_RND(13) TF_RND(15) TF_RND(26) TF_RND(6)
    v0 += k0; v1 += k1 + 3u;
    TF_RND(17) TF_RND(29) TF_RND(16) TF_RND(24)
    v0 += k1; v1 += k2 + 4u;
    TF_RND(13) TF_RND(15) TF_RND(26) TF_RND(6)
    v0 += k2; v1 += k0 + 5u;
#undef TF_RND

    return v0 ^ v1;          // XOR-fold of the 2x32 PRF output
}

__device__ __forceinline__ int sparse_at(int i) {
    unsigned bits = threefry_bits((unsigned)i);
    unsigned fb = (bits >> 9) | 0x3f800000u;
    float u = __uint_as_float(fb) - 1.0f;   // uniform in [0,1), 23 mantissa bits
    return (u < 0.065f) ? 1 : 0;
}

// ---------------- Fused kernel: ballot mask + masked streaming copy ---------
// Block = 32 consecutive positions of one row. Each wave redundantly builds
// the mask in SGPRs via two ballots (no LDS, no barriers), then streams its
// 8 positions with a scalar (wave-uniform) masked/copy branch.
// NOTE (r6-r8 post-mortems): pointer-select, per-position branch diamonds,
// and 3-way run specialization ALL regressed 6-10us vs this shape. With 8
// blocks/CU the memory pipe is saturated by TLP; keep the simple
// one-load/one-store iteration with induction-variable addressing.
__global__ __launch_bounds__(256) void fused_kernel(const vfloat4* __restrict__ seq,
                                                    const vfloat4* __restrict__ mi,
                                                    float* __restrict__ maskf,
                                                    vfloat4* __restrict__ out) {
    const int t = threadIdx.x;
    const int lane = t & 63;
    const int w = t >> 6;                   // wave id 0..3
    const int base = blockIdx.x * POS_PER_BLK;
    const int rowstart = base & ~(SS - 1);  // rows are 4096-aligned

    // Ballot 1: bit l = sparse(base-5+l), l = 0..40 (halo), clamped to row
    int sv = 0;
    {
        const int p = base - 5 + lane;
        if (lane <= 40 && p >= rowstart && p < rowstart + SS) sv = sparse_at(p);
    }
    const unsigned long long bal = __ballot(sv);

    // Ballot 2: bit t0 = dilated mask of position base+t0 (t0 = 0..31)
    int m_t = 0;
    if (lane < 32) {
        const int j = (base + lane) & (SS - 1);
        if (j == SS - 1) m_t = (int)((bal >> (lane + 5)) & 1ull);  // sparse only
        else             m_t = ((bal >> lane) & 0x3FFull) != 0ull; // window [j-5, j+4]
    }
    const unsigned M = (unsigned)__ballot(m_t);   // 32 mask bits, SGPR

    if (t < 32) maskf[base + t] = (float)((M >> t) & 1u);  // second output

    // Streaming: wave w owns f4 range [w*1024, (w+1)*1024) of this block
    const long long blk_f4 = (long long)blockIdx.x * F4_PER_BLK;
    const int wbase = w * F4_PER_WAVE;
    const int posbase = __builtin_amdgcn_readfirstlane(w * 8);
#pragma unroll
    for (int it = 0; it < 16; ++it) {
        const int k = wbase + it * 64 + lane;
        const int pos = posbase + (it >> 1);          // scalar + compile-time
        vfloat4 v;
        if ((M >> pos) & 1u) {                        // wave-uniform scalar branch
            v = mi[k & (F4_PER_POS - 1)];             // 2KB, L1-resident
        } else {
            v = __builtin_nontemporal_load(&seq[blk_f4 + k]);
        }
        __builtin_nontemporal_store(v, &out[blk_f4 + k]);
    }
}

extern "C" void kernel_launch(void* const* d_in, const int* in_sizes, int n_in,
                              void* d_out, int out_size, void* d_ws, size_t ws_size,
                              hipStream_t stream) {
    const float* seq = (const float*)d_in[0];
    const float* mask_item = (const float*)d_in[1];
    float* out = (float*)d_out;
    float* maskf = out + OUT_ELEMS;         // tuple output #2 lives at the tail

    fused_kernel<<<NPOS / POS_PER_BLK, 256, 0, stream>>>((const vfloat4*)seq,
                                                         (const vfloat4*)mask_item,
                                                         maskf,
                                                         (vfloat4*)out);
}